// Round 1
// baseline (1313.498 us; speedup 1.0000x reference)
//
#include <hip/hip_runtime.h>

#define NEG_SLOPE 0.2f

// One 64-lane wave per edge; lane d handles dim d of the 64-wide embedding row.
// Gather emb[col] (256B contiguous per wave) and atomicAdd into acc[row]
// (256B contiguous per wave). Grid-stride over edges.
__global__ void spmm_scatter_kernel(const float* __restrict__ emb,
                                    const int* __restrict__ row,
                                    const int* __restrict__ col,
                                    const float* __restrict__ val,
                                    float* __restrict__ acc,
                                    int n_edges) {
    const int lane = threadIdx.x & 63;
    const int waves_per_block = blockDim.x >> 6;
    const int wave_in_block = threadIdx.x >> 6;
    const int total_waves = gridDim.x * waves_per_block;
    for (int e = blockIdx.x * waves_per_block + wave_in_block; e < n_edges; e += total_waves) {
        const int r = row[e];
        const int c = col[e];
        const float v = val[e];
        const float m = v * emb[(size_t)c * 64 + lane];
        atomicAdd(&acc[(size_t)r * 64 + lane], m);
    }
}

// In-place: io[r] = leaky_relu(io[r] @ W), W selected per row range.
// One wave per row: lane j owns output dim j; h broadcast via __shfl.
__global__ void transform_leaky_kernel(float* __restrict__ io,
                                       const float* __restrict__ W_u,
                                       const float* __restrict__ W_i,
                                       int n_u_rows,
                                       int n_total_rows) {
    __shared__ float Ws[2][64 * 64];
    for (int i = threadIdx.x; i < 64 * 64; i += blockDim.x) {
        Ws[0][i] = W_u[i];
        Ws[1][i] = W_i[i];
    }
    __syncthreads();

    const int lane = threadIdx.x & 63;
    const int waves_per_block = blockDim.x >> 6;
    const int wave_in_block = threadIdx.x >> 6;
    const int total_waves = gridDim.x * waves_per_block;

    for (int r = blockIdx.x * waves_per_block + wave_in_block; r < n_total_rows; r += total_waves) {
        const float* W = (r < n_u_rows) ? Ws[0] : Ws[1];
        const float hv = io[(size_t)r * 64 + lane];
        float acc = 0.0f;
        #pragma unroll
        for (int k = 0; k < 64; ++k) {
            const float hk = __shfl(hv, k, 64);
            acc = fmaf(hk, W[k * 64 + lane], acc);
        }
        const float o = acc > 0.0f ? acc : NEG_SLOPE * acc;
        io[(size_t)r * 64 + lane] = o;
    }
}

extern "C" void kernel_launch(void* const* d_in, const int* in_sizes, int n_in,
                              void* d_out, int out_size, void* d_ws, size_t ws_size,
                              hipStream_t stream) {
    const float* users_emb = (const float*)d_in[0];
    const float* items_emb = (const float*)d_in[1];
    const int*   u_row     = (const int*)d_in[2];
    const int*   u_col     = (const int*)d_in[3];
    const float* u_val     = (const float*)d_in[4];
    const int*   i_row     = (const int*)d_in[5];
    const int*   i_col     = (const int*)d_in[6];
    const float* i_val     = (const float*)d_in[7];
    const float* W_u       = (const float*)d_in[8];
    const float* W_i       = (const float*)d_in[9];

    const int n_u = in_sizes[0] / 64;   // 100000
    const int n_i = in_sizes[1] / 64;   // 200000
    const int e_u = in_sizes[2];        // 1.6M
    const int e_i = in_sizes[5];        // 3.2M

    float* out   = (float*)d_out;
    float* out_u = out;
    float* out_i = out + (size_t)n_u * 64;

    // Zero the accumulator (= output buffer) every call for determinism.
    hipMemsetAsync(d_out, 0, (size_t)out_size * sizeof(float), stream);

    // Scatter phase. 256 threads = 4 waves/block; cap grid and grid-stride.
    const int BLK = 256;
    const int WPB = BLK / 64;
    int grid_u = (e_u + WPB - 1) / WPB;
    int grid_i = (e_i + WPB - 1) / WPB;
    const int GRID_CAP = 256 * 8;  // 256 CUs x 8 blocks
    if (grid_u > GRID_CAP) grid_u = GRID_CAP;
    if (grid_i > GRID_CAP) grid_i = GRID_CAP;

    spmm_scatter_kernel<<<grid_u, BLK, 0, stream>>>(users_emb, u_row, u_col, u_val, out_u, e_u);
    spmm_scatter_kernel<<<grid_i, BLK, 0, stream>>>(items_emb, i_row, i_col, i_val, out_i, e_i);

    // In-place transform + leaky relu over all 300000 rows.
    const int n_rows = n_u + n_i;
    int grid_t = (n_rows + WPB - 1) / WPB;
    if (grid_t > GRID_CAP) grid_t = GRID_CAP;
    transform_leaky_kernel<<<grid_t, BLK, 0, stream>>>(out, W_u, W_i, n_u, n_rows);
}

// Round 2
// 1019.442 us; speedup vs baseline: 1.2884x; 1.2884x over previous
//
#include <hip/hip_runtime.h>

#define NEG_SLOPE 0.2f

// ---------------------------------------------------------------------------
// Fallback path (round-1): edge-parallel atomic scatter.
// ---------------------------------------------------------------------------
__global__ void spmm_scatter_kernel(const float* __restrict__ emb,
                                    const int* __restrict__ row,
                                    const int* __restrict__ col,
                                    const float* __restrict__ val,
                                    float* __restrict__ acc,
                                    int n_edges) {
    const int lane = threadIdx.x & 63;
    const int waves_per_block = blockDim.x >> 6;
    const int wave_in_block = threadIdx.x >> 6;
    const int total_waves = gridDim.x * waves_per_block;
    for (int e = blockIdx.x * waves_per_block + wave_in_block; e < n_edges; e += total_waves) {
        const int r = row[e];
        const int c = col[e];
        const float v = val[e];
        const float m = v * emb[(size_t)c * 64 + lane];
        atomicAdd(&acc[(size_t)r * 64 + lane], m);
    }
}

// ---------------------------------------------------------------------------
// CSR build: histogram -> exclusive scan (3 kernels) -> reorder
// ---------------------------------------------------------------------------
__global__ void hist_kernel(const int* __restrict__ rows, int n_edges, int row_off,
                            int* __restrict__ counts) {
    const int stride = gridDim.x * blockDim.x;
    for (int e = blockIdx.x * blockDim.x + threadIdx.x; e < n_edges; e += stride) {
        atomicAdd(&counts[row_off + rows[e]], 1);
    }
}

// 512-thread blocks; block b sums counts[b*512 .. b*512+511] -> partials[b]
__global__ void scan_part1_kernel(const int* __restrict__ counts, int n,
                                  int* __restrict__ partials) {
    __shared__ int s[512];
    const int gi = blockIdx.x * 512 + threadIdx.x;
    s[threadIdx.x] = (gi < n) ? counts[gi] : 0;
    __syncthreads();
    for (int off = 256; off > 0; off >>= 1) {
        if (threadIdx.x < off) s[threadIdx.x] += s[threadIdx.x + off];
        __syncthreads();
    }
    if (threadIdx.x == 0) partials[blockIdx.x] = s[0];
}

// one 1024-thread block: exclusive scan of partials[nb] (nb <= 1024)
__global__ void scan_part2_kernel(int* __restrict__ partials, int nb) {
    __shared__ int s[1024];
    const int tid = threadIdx.x;
    int v = (tid < nb) ? partials[tid] : 0;
    s[tid] = v;
    __syncthreads();
    for (int off = 1; off < 1024; off <<= 1) {
        int t = (tid >= off) ? s[tid - off] : 0;
        __syncthreads();
        s[tid] += t;
        __syncthreads();
    }
    if (tid < nb) partials[tid] = s[tid] - v;  // exclusive
}

// 512-thread blocks: exclusive scan within chunk + add partial base -> row_ptr
__global__ void scan_part3_kernel(const int* __restrict__ counts, int n,
                                  const int* __restrict__ partials,
                                  int* __restrict__ row_ptr) {
    __shared__ int s[512];
    const int tid = threadIdx.x;
    const int gi = blockIdx.x * 512 + tid;
    const int v = (gi < n) ? counts[gi] : 0;
    s[tid] = v;
    __syncthreads();
    for (int off = 1; off < 512; off <<= 1) {
        int t = (tid >= off) ? s[tid - off] : 0;
        __syncthreads();
        s[tid] += t;
        __syncthreads();
    }
    const int base = partials[blockIdx.x];
    if (gi < n) {
        row_ptr[gi] = base + s[tid] - v;          // exclusive
        if (gi == n - 1) row_ptr[n] = base + s[tid];  // total
    }
}

__global__ void reorder_kernel(const int* __restrict__ rows,
                               const int* __restrict__ cols,
                               const float* __restrict__ vals,
                               int n_edges, int row_off,
                               const int* __restrict__ row_ptr,
                               int* __restrict__ cursor,
                               int* __restrict__ csr_src,
                               float* __restrict__ csr_val) {
    const int stride = gridDim.x * blockDim.x;
    for (int e = blockIdx.x * blockDim.x + threadIdx.x; e < n_edges; e += stride) {
        const int r = row_off + rows[e];
        const int pos = row_ptr[r] + atomicAdd(&cursor[r], 1);
        csr_src[pos] = cols[e];
        csr_val[pos] = vals[e];
    }
}

// ---------------------------------------------------------------------------
// Gather: one wave per output row. Coalesced load of the row's (src,val)
// segment, __shfl broadcast, register accumulate, one 256B store per row.
// ---------------------------------------------------------------------------
__global__ void csr_gather_kernel(const float* __restrict__ users_emb,
                                  const float* __restrict__ items_emb,
                                  const int* __restrict__ row_ptr,
                                  const int* __restrict__ csr_src,
                                  const float* __restrict__ csr_val,
                                  float* __restrict__ out,
                                  int n_u, int n_rows) {
    const int lane = threadIdx.x & 63;
    const int waves_per_block = blockDim.x >> 6;
    const int wave_in_block = threadIdx.x >> 6;
    const int total_waves = gridDim.x * waves_per_block;

    for (int r = blockIdx.x * waves_per_block + wave_in_block; r < n_rows; r += total_waves) {
        const int start = row_ptr[r];
        const int end = row_ptr[r + 1];
        const float* __restrict__ base = (r < n_u) ? users_emb : items_emb;
        float acc = 0.0f;
        for (int j0 = start; j0 < end; j0 += 64) {
            const int nj = min(64, end - j0);
            int s = 0;
            float v = 0.0f;
            if (lane < nj) {
                s = csr_src[j0 + lane];
                v = csr_val[j0 + lane];
            }
            for (int k = 0; k < nj; ++k) {
                const int sk = __shfl(s, k, 64);
                const float vk = __shfl(v, k, 64);
                acc = fmaf(vk, base[(size_t)sk * 64 + lane], acc);
            }
        }
        out[(size_t)r * 64 + lane] = acc;
    }
}

// ---------------------------------------------------------------------------
// In-place: io[r] = leaky_relu(io[r] @ W), W selected per row range.
// ---------------------------------------------------------------------------
__global__ void transform_leaky_kernel(float* __restrict__ io,
                                       const float* __restrict__ W_u,
                                       const float* __restrict__ W_i,
                                       int n_u_rows,
                                       int n_total_rows) {
    __shared__ float Ws[2][64 * 64];
    for (int i = threadIdx.x; i < 64 * 64; i += blockDim.x) {
        Ws[0][i] = W_u[i];
        Ws[1][i] = W_i[i];
    }
    __syncthreads();

    const int lane = threadIdx.x & 63;
    const int waves_per_block = blockDim.x >> 6;
    const int wave_in_block = threadIdx.x >> 6;
    const int total_waves = gridDim.x * waves_per_block;

    for (int r = blockIdx.x * waves_per_block + wave_in_block; r < n_total_rows; r += total_waves) {
        const float* W = (r < n_u_rows) ? Ws[0] : Ws[1];
        const float hv = io[(size_t)r * 64 + lane];
        float acc = 0.0f;
        #pragma unroll
        for (int k = 0; k < 64; ++k) {
            const float hk = __shfl(hv, k, 64);
            acc = fmaf(hk, W[k * 64 + lane], acc);
        }
        const float o = acc > 0.0f ? acc : NEG_SLOPE * acc;
        io[(size_t)r * 64 + lane] = o;
    }
}

extern "C" void kernel_launch(void* const* d_in, const int* in_sizes, int n_in,
                              void* d_out, int out_size, void* d_ws, size_t ws_size,
                              hipStream_t stream) {
    const float* users_emb = (const float*)d_in[0];
    const float* items_emb = (const float*)d_in[1];
    const int*   u_row     = (const int*)d_in[2];
    const int*   u_col     = (const int*)d_in[3];
    const float* u_val     = (const float*)d_in[4];
    const int*   i_row     = (const int*)d_in[5];
    const int*   i_col     = (const int*)d_in[6];
    const float* i_val     = (const float*)d_in[7];
    const float* W_u       = (const float*)d_in[8];
    const float* W_i       = (const float*)d_in[9];

    const int n_u = in_sizes[0] / 64;   // 100000
    const int n_i = in_sizes[1] / 64;   // 200000
    const int e_u = in_sizes[2];        // 1.6M
    const int e_i = in_sizes[5];        // 3.2M
    const int n_rows = n_u + n_i;       // 300000
    const long long E = (long long)e_u + e_i;  // 4.8M

    float* out = (float*)d_out;

    const int BLK = 256;
    const int WPB = BLK / 64;
    const int GRID_CAP = 2048;

    // Workspace layout (4B units):
    //   counts [n_rows] | row_ptr [n_rows+1] | cursor [n_rows] |
    //   partials [nb]   | csr_src [E]        | csr_val [E]
    const int nb = (n_rows + 511) / 512;  // scan blocks (586 <= 1024)
    const size_t need_words = (size_t)3 * n_rows + 1 + nb + 2 * (size_t)E;
    const size_t need_bytes = need_words * 4;

    if (ws_size >= need_bytes && nb <= 1024) {
        int* counts   = (int*)d_ws;
        int* row_ptr  = counts + n_rows;
        int* cursor   = row_ptr + (n_rows + 1);
        int* partials = cursor + n_rows;
        int* csr_src  = partials + nb;
        float* csr_val = (float*)(csr_src + E);

        // zero counts + cursor
        hipMemsetAsync(counts, 0, (size_t)n_rows * 4, stream);
        hipMemsetAsync(cursor, 0, (size_t)n_rows * 4, stream);

        // histogram
        hist_kernel<<<GRID_CAP, BLK, 0, stream>>>(u_row, e_u, 0, counts);
        hist_kernel<<<GRID_CAP, BLK, 0, stream>>>(i_row, e_i, n_u, counts);

        // exclusive scan -> row_ptr
        scan_part1_kernel<<<nb, 512, 0, stream>>>(counts, n_rows, partials);
        scan_part2_kernel<<<1, 1024, 0, stream>>>(partials, nb);
        scan_part3_kernel<<<nb, 512, 0, stream>>>(counts, n_rows, partials, row_ptr);

        // reorder edges into CSR
        reorder_kernel<<<GRID_CAP, BLK, 0, stream>>>(u_row, u_col, u_val, e_u, 0,
                                                     row_ptr, cursor, csr_src, csr_val);
        reorder_kernel<<<GRID_CAP, BLK, 0, stream>>>(i_row, i_col, i_val, e_i, n_u,
                                                     row_ptr, cursor, csr_src, csr_val);

        // gather (writes every output row; no memset of d_out needed)
        int grid_g = (n_rows + WPB - 1) / WPB;
        if (grid_g > GRID_CAP) grid_g = GRID_CAP;
        csr_gather_kernel<<<grid_g, BLK, 0, stream>>>(users_emb, items_emb, row_ptr,
                                                      csr_src, csr_val, out, n_u, n_rows);
    } else {
        // Fallback: atomic scatter (round-1 path)
        float* out_u = out;
        float* out_i = out + (size_t)n_u * 64;
        hipMemsetAsync(d_out, 0, (size_t)out_size * sizeof(float), stream);
        int grid_u = (e_u + WPB - 1) / WPB;
        int grid_i = (e_i + WPB - 1) / WPB;
        const int SCAP = 256 * 8;
        if (grid_u > SCAP) grid_u = SCAP;
        if (grid_i > SCAP) grid_i = SCAP;
        spmm_scatter_kernel<<<grid_u, BLK, 0, stream>>>(users_emb, u_row, u_col, u_val, out_u, e_u);
        spmm_scatter_kernel<<<grid_i, BLK, 0, stream>>>(items_emb, i_row, i_col, i_val, out_i, e_i);
    }

    // in-place transform + leaky relu over all rows
    int grid_t = (n_rows + WPB - 1) / WPB;
    if (grid_t > GRID_CAP) grid_t = GRID_CAP;
    transform_leaky_kernel<<<grid_t, BLK, 0, stream>>>(out, W_u, W_i, n_u, n_rows);
}